// Round 3
// baseline (212.673 us; speedup 1.0000x reference)
//
#include <hip/hip_runtime.h>
#include <stdint.h>

#define N_NODES 30000
#define NC 256

typedef _Float16 f16x8 __attribute__((ext_vector_type(8)));
typedef _Float16 f16x4 __attribute__((ext_vector_type(4)));
typedef _Float16 f16x2 __attribute__((ext_vector_type(2)));
typedef float f32x4 __attribute__((ext_vector_type(4)));

// ---- convert x (with clip +-10) to f16 ----
__global__ void k_conv_x(const float* __restrict__ x, _Float16* __restrict__ xb) {
    int i = (blockIdx.x * 256 + threadIdx.x) * 4;   // total 7,680,000 -> 7500 blocks
    float4 v = *reinterpret_cast<const float4*>(x + i);
    f16x4 o;
    o[0] = (_Float16)fminf(fmaxf(v.x, -10.f), 10.f);
    o[1] = (_Float16)fminf(fmaxf(v.y, -10.f), 10.f);
    o[2] = (_Float16)fminf(fmaxf(v.z, -10.f), 10.f);
    o[3] = (_Float16)fminf(fmaxf(v.w, -10.f), 10.f);
    *reinterpret_cast<f16x4*>(xb + i) = o;
}

// ---- convert W = [w_real; w_imag] ([512][256]) to f16 ----
__global__ void k_conv_w(const float* __restrict__ wr, const float* __restrict__ wi,
                         _Float16* __restrict__ Wb) {
    int i = (blockIdx.x * 256 + threadIdx.x) * 4;   // total 131,072 -> 128 blocks
    const float* src = (i < NC * NC) ? (wr + i) : (wi + (i - NC * NC));
    float4 v = *reinterpret_cast<const float4*>(src);
    f16x4 o;
    o[0] = (_Float16)v.x; o[1] = (_Float16)v.y;
    o[2] = (_Float16)v.z; o[3] = (_Float16)v.w;
    *reinterpret_cast<f16x4*>(Wb + i) = o;
}

// ---- prep: per-node complex coefficient P_s = esc*1e-4*subH[0][s]*mask[s]/||H||_F
__global__ void k_prep(const float* __restrict__ subH, const float* __restrict__ sub_mask,
                       const float* __restrict__ escp, float* __restrict__ c4) {
    int node = blockIdx.x * 256 + threadIdx.x;      // 118 blocks
    if (node >= N_NODES) return;
    float esc = *escp;
    const float4* Hp = reinterpret_cast<const float4*>(subH + node * 16);
    float4 r0 = Hp[0], r1 = Hp[1], r2 = Hp[2], r3 = Hp[3];
    float fr = r0.x * r0.x + r0.y * r0.y + r0.z * r0.z + r0.w * r0.w
             + r1.x * r1.x + r1.y * r1.y + r1.z * r1.z + r1.w * r1.w
             + r2.x * r2.x + r2.y * r2.y + r2.z * r2.z + r2.w * r2.w
             + r3.x * r3.x + r3.y * r3.y + r3.z * r3.z + r3.w * r3.w;
    float coef = 1e-4f * rsqrtf(fr) * esc;
    float4 m = *reinterpret_cast<const float4*>(sub_mask + node * 4);
    float4 o;
    o.x = coef * r0.x * m.x;
    o.y = coef * r0.y * m.y;
    o.z = coef * r0.z * m.z;
    o.w = coef * r0.w * m.w;
    *reinterpret_cast<float4*>(c4 + node * 4) = o;
}

// ---- GEMM v5: high-occupancy register GEMM ----
// R2 counters (v3): 44us, MfmaUtil 6.3, VALUBusy 6.1, HBM 13%, Occ 16.7% ->
// latency-bound: 470 blocks = 1880 waves (23% ceiling) and 128-VGPR A-preload.
// v5: wave tile 32x64 (acc 32 VGPR), A loaded per K-step, col-tile in grid:
// 469 x 4 = 1876 blocks = 7504 waves (92% ceiling), launch_bounds(256,4).
// A re-read 8x logically but L3-resident (15 MB); HBM traffic unchanged.
// BW floor ~46 MB -> 7.3us.
__global__ __launch_bounds__(256, 4) void k_gemm(
    const _Float16* __restrict__ A, const _Float16* __restrict__ B,
    const float* __restrict__ br, const float* __restrict__ bi,
    _Float16* __restrict__ H)
{
    int bid = blockIdx.x;
    int bm = bid >> 2, cns = bid & 3;         // 469 x 4 blocks
    int tid = threadIdx.x;
    int lane = tid & 63, wave = tid >> 6;
    int quad = lane >> 4, l16 = lane & 15;
    int wm = wave >> 1, wn = wave & 1;        // wm: 32-row half; wn: re/im parity
    int row0 = bm * 64 + wm * 32;

    int r0 = row0 + l16;
    int r1 = row0 + 16 + l16;
    if (r0 >= N_NODES) r0 = N_NODES - 1;      // clamp: garbage rows never stored
    if (r1 >= N_NODES) r1 = N_NODES - 1;
    const _Float16* ap0 = A + r0 * NC + quad * 8;
    const _Float16* ap1 = A + r1 * NC + quad * 8;

    const float* bias_p = wn ? bi : br;
    const _Float16* bbase = B + ((wn ? 256 : 0) + cns * 64 + l16) * NC + quad * 8;

    f32x4 acc[2][4] = {};
#pragma unroll
    for (int kc = 0; kc < 8; kc++) {
        f16x8 a0 = *reinterpret_cast<const f16x8*>(ap0 + kc * 32);
        f16x8 a1 = *reinterpret_cast<const f16x8*>(ap1 + kc * 32);
        f16x8 b0 = *reinterpret_cast<const f16x8*>(bbase + 0 * 16 * NC + kc * 32);
        f16x8 b1 = *reinterpret_cast<const f16x8*>(bbase + 1 * 16 * NC + kc * 32);
        f16x8 b2 = *reinterpret_cast<const f16x8*>(bbase + 2 * 16 * NC + kc * 32);
        f16x8 b3 = *reinterpret_cast<const f16x8*>(bbase + 3 * 16 * NC + kc * 32);
        acc[0][0] = __builtin_amdgcn_mfma_f32_16x16x32_f16(a0, b0, acc[0][0], 0, 0, 0);
        acc[0][1] = __builtin_amdgcn_mfma_f32_16x16x32_f16(a0, b1, acc[0][1], 0, 0, 0);
        acc[0][2] = __builtin_amdgcn_mfma_f32_16x16x32_f16(a0, b2, acc[0][2], 0, 0, 0);
        acc[0][3] = __builtin_amdgcn_mfma_f32_16x16x32_f16(a0, b3, acc[0][3], 0, 0, 0);
        acc[1][0] = __builtin_amdgcn_mfma_f32_16x16x32_f16(a1, b0, acc[1][0], 0, 0, 0);
        acc[1][1] = __builtin_amdgcn_mfma_f32_16x16x32_f16(a1, b1, acc[1][1], 0, 0, 0);
        acc[1][2] = __builtin_amdgcn_mfma_f32_16x16x32_f16(a1, b2, acc[1][2], 0, 0, 0);
        acc[1][3] = __builtin_amdgcn_mfma_f32_16x16x32_f16(a1, b3, acc[1][3], 0, 0, 0);
    }
#pragma unroll
    for (int ni = 0; ni < 4; ni++) {
        int c = cns * 64 + ni * 16 + l16;
        float bias = bias_p[c];
        int cc = 2 * c + wn;
#pragma unroll
        for (int mi = 0; mi < 2; mi++) {
            int rowb = row0 + mi * 16 + quad * 4;
#pragma unroll
            for (int r = 0; r < 4; r++) {
                int row = rowb + r;
                if (row < N_NODES)
                    H[row * 512 + cc] = (_Float16)(acc[mi][ni][r] + bias);
            }
        }
    }
}

// ---- evolve v4: NPB=60 / 512 threads (8 groups) / 500 blocks; coef precomputed
// by k_prep; 2-deep software pipeline on the j-loop. (R2: dropped out of top-5.)
#define NPB 60
#define NGRP 8
__global__ __launch_bounds__(512) void k_evolve(
    const float* __restrict__ x, const int* __restrict__ sub_nodes,
    const float* __restrict__ c4, const _Float16* __restrict__ h,
    const float* __restrict__ escp,
    float* __restrict__ outz, _Float16* __restrict__ zbuf, int use_f16,
    float* __restrict__ ssum, float* __restrict__ ssumsq)
{
    __shared__ int   s_nodes[NPB][4];
    __shared__ float s_P[NPB][4];
    __shared__ float s_redA[NGRP][256];
    __shared__ float s_redB[NGRP][256];
    int tid = threadIdx.x;
    int g = tid >> 6, lane = tid & 63;
    int base = blockIdx.x * NPB;      // 30000 = 500*60 exactly
    if (tid < NPB) {
        int node = base + tid;
        *reinterpret_cast<float4*>(&s_P[tid][0]) =
            *reinterpret_cast<const float4*>(c4 + node * 4);
        *reinterpret_cast<int4*>(&s_nodes[tid][0]) =
            *reinterpret_cast<const int4*>(sub_nodes + node * 4);
    }
    __syncthreads();
    float esc = *escp;
    float lsum[4] = {0.f, 0.f, 0.f, 0.f};
    float lsq[4]  = {0.f, 0.f, 0.f, 0.f};

    f16x8 hvA[4];
    float4 xA;
    int j = g;
#pragma unroll
    for (int s = 0; s < 4; s++)
        hvA[s] = *reinterpret_cast<const f16x8*>(h + s_nodes[j][s] * 512 + lane * 8);
    xA = *reinterpret_cast<const float4*>(x + (base + j) * NC + lane * 4);

    for (;;) {
        int jn = j + NGRP;
        bool more = jn < NPB;
        f16x8 hvB[4];
        float4 xB;
        if (more) {
#pragma unroll
            for (int s = 0; s < 4; s++)
                hvB[s] = *reinterpret_cast<const f16x8*>(
                    h + s_nodes[jn][s] * 512 + lane * 8);
            xB = *reinterpret_cast<const float4*>(x + (base + jn) * NC + lane * 4);
        }
        // ---- compute node j from hvA/xA ----
        {
            int node = base + j;
            float P0 = s_P[j][0], P1 = s_P[j][1], P2 = s_P[j][2], P3 = s_P[j][3];
            float xr[4] = {xA.x, xA.y, xA.z, xA.w};
            f16x8 zo;
            float or4[4], oi4[4];
#pragma unroll
            for (int e = 0; e < 4; e++) {
                float hr0 = (float)hvA[0][2 * e], hi0 = (float)hvA[0][2 * e + 1];
                float hr1 = (float)hvA[1][2 * e], hi1 = (float)hvA[1][2 * e + 1];
                float hr2 = (float)hvA[2][2 * e], hi2 = (float)hvA[2][2 * e + 1];
                float hr3 = (float)hvA[3][2 * e], hi3 = (float)hvA[3][2 * e + 1];
                float er = esc * hr0;             // identity (self) term, m0==1
                float ei = esc * hi0;
                er = fmaf(P0, hi0, er); ei = fmaf(-P0, hr0, ei);
                er = fmaf(P1, hi1, er); ei = fmaf(-P1, hr1, ei);
                er = fmaf(P2, hi2, er); ei = fmaf(-P2, hr2, ei);
                er = fmaf(P3, hi3, er); ei = fmaf(-P3, hr3, ei);
                float outr = er + xr[e];
                float outi = ei;
                or4[e] = outr; oi4[e] = outi;
                zo[2 * e] = (_Float16)outr; zo[2 * e + 1] = (_Float16)outi;
                float mag = sqrtf(fmaf(outr, outr, fmaf(outi, outi, 1e-5f)));
                mag = fminf(fmaxf(mag, 1e-5f), 1000.f);
                lsum[e] += mag;
                lsq[e] = fmaf(mag, mag, lsq[e]);
            }
            if (use_f16) {
                *reinterpret_cast<f16x8*>(zbuf + node * 512 + lane * 8) = zo;
            } else {
                *reinterpret_cast<float4*>(outz + node * 512 + lane * 4) =
                    make_float4(or4[0], or4[1], or4[2], or4[3]);
                *reinterpret_cast<float4*>(outz + node * 512 + 256 + lane * 4) =
                    make_float4(oi4[0], oi4[1], oi4[2], oi4[3]);
            }
        }
        if (!more) break;
#pragma unroll
        for (int s = 0; s < 4; s++) hvA[s] = hvB[s];
        xA = xB;
        j = jn;
    }
#pragma unroll
    for (int e = 0; e < 4; e++) {
        s_redA[g][lane * 4 + e] = lsum[e];
        s_redB[g][lane * 4 + e] = lsq[e];
    }
    __syncthreads();
    if (tid < 256) {
        float a = 0.f;
#pragma unroll
        for (int q = 0; q < NGRP; q++) a += s_redA[q][tid];
        atomicAdd(&ssum[tid], a);          // tid == channel; 500 adds per address
    } else {
        int t = tid - 256;
        float b = 0.f;
#pragma unroll
        for (int q = 0; q < NGRP; q++) b += s_redB[q][t];
        atomicAdd(&ssumsq[t], b);
    }
}

// ---- layernorm + phase + leaky crelu; stats affine recomputed inline ----
__global__ __launch_bounds__(256) void k_norm(
    float* __restrict__ out, const _Float16* __restrict__ zbuf, int use_f16,
    const float* __restrict__ ssum, const float* __restrict__ ssumsq,
    const float* __restrict__ lnw, const float* __restrict__ lnb)
{
    int tid = threadIdx.x;
    int node = blockIdx.x * 4 + (tid >> 6);        // 7500 blocks
    int c0 = (tid & 63) * 4;
    float re[4], im[4];
    if (use_f16) {
        f16x8 z = *reinterpret_cast<const f16x8*>(zbuf + node * 512 + c0 * 2);
#pragma unroll
        for (int e = 0; e < 4; e++) { re[e] = (float)z[2 * e]; im[e] = (float)z[2 * e + 1]; }
    } else {
        float4 r4 = *reinterpret_cast<const float4*>(out + node * 512 + c0);
        float4 i4 = *reinterpret_cast<const float4*>(out + node * 512 + 256 + c0);
        re[0] = r4.x; re[1] = r4.y; re[2] = r4.z; re[3] = r4.w;
        im[0] = i4.x; im[1] = i4.y; im[2] = i4.z; im[3] = i4.w;
    }
    float4 s4 = *reinterpret_cast<const float4*>(ssum + c0);
    float4 q4 = *reinterpret_cast<const float4*>(ssumsq + c0);
    float4 w4 = *reinterpret_cast<const float4*>(lnw + c0);
    float4 lb4 = *reinterpret_cast<const float4*>(lnb + c0);
    float S[4] = {s4.x, s4.y, s4.z, s4.w};
    float Q[4] = {q4.x, q4.y, q4.z, q4.w};
    float W[4] = {w4.x, w4.y, w4.z, w4.w};
    float L[4] = {lb4.x, lb4.y, lb4.z, lb4.w};
    const float invN = 1.0f / (float)N_NODES;
    float orr[4], oii[4];
#pragma unroll
    for (int e = 0; e < 4; e++) {
        float mean = S[e] * invN;
        float var = fmaxf(Q[e] * invN - mean * mean, 0.f);
        float denom = sqrtf(var + 1e-5f) + 1e-5f;
        float A = fabsf(W[e]) / denom;
        float Bc = L[e] - mean * A;
        float r = re[e], i = im[e];
        float mag = sqrtf(fmaf(r, r, fmaf(i, i, 1e-5f)));
        mag = fminf(fmaxf(mag, 1e-5f), 1000.f);
        float sm = fmaf(mag, A, Bc);
        sm = fminf(fmaxf(sm, 1e-5f), 10.0f);
        float px = fminf(fmaxf(r, -1e6f), 1e6f) + 1e-10f;
        float py = fminf(fmaxf(i, -1e6f), 1e6f);
        float r2 = fmaf(px, px, py * py);
        float inv = rsqrtf(r2);
        float zr = sm * px * inv, zi = sm * py * inv;
        zr = fminf(fmaxf(zr, -5.f), 5.f);
        zi = fminf(fmaxf(zi, -5.f), 5.f);
        orr[e] = zr > 0.f ? zr : 0.01f * zr;
        oii[e] = zi > 0.f ? zi : 0.01f * zi;
    }
    *reinterpret_cast<float4*>(out + node * 512 + c0) =
        make_float4(orr[0], orr[1], orr[2], orr[3]);
    *reinterpret_cast<float4*>(out + node * 512 + 256 + c0) =
        make_float4(oii[0], oii[1], oii[2], oii[3]);
}

extern "C" void kernel_launch(void* const* d_in, const int* in_sizes, int n_in,
                              void* d_out, int out_size, void* d_ws, size_t ws_size,
                              hipStream_t stream) {
    const float* x        = (const float*)d_in[0];
    // d_in[1] edge_index: unused (sub_nodes/sub_mask/sub_H are precomputed)
    const int*   sub_nodes = (const int*)d_in[2];
    const float* sub_mask  = (const float*)d_in[3];
    const float* subH      = (const float*)d_in[4];
    const float* wr  = (const float*)d_in[5];
    const float* wi  = (const float*)d_in[6];
    const float* br  = (const float*)d_in[7];
    const float* bi  = (const float*)d_in[8];
    const float* lnw = (const float*)d_in[9];
    const float* lnb = (const float*)d_in[10];
    const float* esc = (const float*)d_in[11];
    float* out = (float*)d_out;

    char* ws = (char*)d_ws;
    const size_t XB_OFF   = 0;                    // 30000*256*2  = 15,360,000
    const size_t WB_OFF   = 15360000;             // 512*256*2    =    262,144
    const size_t H_OFF    = 15622144;             // 30000*512*2  = 30,720,000
    const size_t STAT_OFF = 46342144;             // 2 * 1024 (alloc 4096)
    const size_t C4_OFF   = 46346240;             // 30000*16     =    480,000
    const size_t ZB_OFF   = 46826240;             // 30000*512*2  = 30,720,000 (optional)
    const size_t WS_NEED_F16 = ZB_OFF + 30720000; // 77,546,240
    _Float16* xb = (_Float16*)(ws + XB_OFF);
    _Float16* Wb = (_Float16*)(ws + WB_OFF);
    _Float16* h  = (_Float16*)(ws + H_OFF);
    float* ssum   = (float*)(ws + STAT_OFF);
    float* ssumsq = (float*)(ws + STAT_OFF + 1024);
    float* c4     = (float*)(ws + C4_OFF);
    _Float16* zbuf = (_Float16*)(ws + ZB_OFF);
    int use_f16 = (ws_size >= WS_NEED_F16) ? 1 : 0;

    hipMemsetAsync(ssum, 0, 2048, stream);
    hipLaunchKernelGGL(k_conv_x, dim3(7500), dim3(256), 0, stream, x, xb);
    hipLaunchKernelGGL(k_conv_w, dim3(128), dim3(256), 0, stream, wr, wi, Wb);
    hipLaunchKernelGGL(k_prep, dim3(118), dim3(256), 0, stream,
                       subH, sub_mask, esc, c4);
    hipLaunchKernelGGL(k_gemm, dim3(469 * 4), dim3(256), 0, stream, xb, Wb, br, bi, h);
    hipLaunchKernelGGL(k_evolve, dim3(500), dim3(512), 0, stream,
                       x, sub_nodes, c4, h, esc, out, zbuf, use_f16,
                       ssum, ssumsq);
    hipLaunchKernelGGL(k_norm, dim3(7500), dim3(256), 0, stream,
                       out, zbuf, use_f16, ssum, ssumsq, lnw, lnb);
}

// Round 4
// 193.702 us; speedup vs baseline: 1.0979x; 1.0979x over previous
//
#include <hip/hip_runtime.h>
#include <stdint.h>

#define N_NODES 30000
#define NC 256

typedef _Float16 f16x8 __attribute__((ext_vector_type(8)));
typedef _Float16 f16x4 __attribute__((ext_vector_type(4)));
typedef _Float16 f16x2 __attribute__((ext_vector_type(2)));
typedef float f32x4 __attribute__((ext_vector_type(4)));

// ---- fused pre-pass: conv_x | conv_w | prep | stats-zero, branch on blockIdx.
// R3 evidence: residual total-minus-kernels is ~90us across all rounds ->
// ~13us/dispatch fixed overhead. Fusing 4 independent pre-kernels (incl. the
// hipMemsetAsync) cuts 7 dispatches to 4. Work is identical to the separate
// kernels; stats-zero ordering is preserved by stream order (k_pre < k_evolve).
#define NBX 7500
#define NBW 128
#define NBP 118
__global__ __launch_bounds__(256) void k_pre(
    const float* __restrict__ x, _Float16* __restrict__ xb,
    const float* __restrict__ wr, const float* __restrict__ wi,
    _Float16* __restrict__ Wb,
    const float* __restrict__ subH, const float* __restrict__ sub_mask,
    const float* __restrict__ escp, float* __restrict__ c4,
    float* __restrict__ ssum, float* __restrict__ ssumsq)
{
    int bid = blockIdx.x, tid = threadIdx.x;
    if (bid < NBX) {
        // conv_x: clip +-10, f32 -> f16
        int i = (bid * 256 + tid) * 4;            // 7,680,000 elements exact
        float4 v = *reinterpret_cast<const float4*>(x + i);
        f16x4 o;
        o[0] = (_Float16)fminf(fmaxf(v.x, -10.f), 10.f);
        o[1] = (_Float16)fminf(fmaxf(v.y, -10.f), 10.f);
        o[2] = (_Float16)fminf(fmaxf(v.z, -10.f), 10.f);
        o[3] = (_Float16)fminf(fmaxf(v.w, -10.f), 10.f);
        *reinterpret_cast<f16x4*>(xb + i) = o;
    } else if (bid < NBX + NBW) {
        // conv_w: [w_real; w_imag] -> f16 [512][256]
        int i = ((bid - NBX) * 256 + tid) * 4;    // 131,072 elements exact
        const float* src = (i < NC * NC) ? (wr + i) : (wi + (i - NC * NC));
        float4 v = *reinterpret_cast<const float4*>(src);
        f16x4 o;
        o[0] = (_Float16)v.x; o[1] = (_Float16)v.y;
        o[2] = (_Float16)v.z; o[3] = (_Float16)v.w;
        *reinterpret_cast<f16x4*>(Wb + i) = o;
    } else if (bid < NBX + NBW + NBP) {
        // prep: P_s = esc*1e-4*subH[0][s]*mask[s]/||H||_F (clamps provably fire)
        int node = (bid - NBX - NBW) * 256 + tid;
        if (node < N_NODES) {
            float esc = *escp;
            const float4* Hp = reinterpret_cast<const float4*>(subH + node * 16);
            float4 r0 = Hp[0], r1 = Hp[1], r2 = Hp[2], r3 = Hp[3];
            float fr = r0.x * r0.x + r0.y * r0.y + r0.z * r0.z + r0.w * r0.w
                     + r1.x * r1.x + r1.y * r1.y + r1.z * r1.z + r1.w * r1.w
                     + r2.x * r2.x + r2.y * r2.y + r2.z * r2.z + r2.w * r2.w
                     + r3.x * r3.x + r3.y * r3.y + r3.z * r3.z + r3.w * r3.w;
            float coef = 1e-4f * rsqrtf(fr) * esc;
            float4 m = *reinterpret_cast<const float4*>(sub_mask + node * 4);
            float4 o;
            o.x = coef * r0.x * m.x;
            o.y = coef * r0.y * m.y;
            o.z = coef * r0.z * m.z;
            o.w = coef * r0.w * m.w;
            *reinterpret_cast<float4*>(c4 + node * 4) = o;
        }
    } else {
        // stats zero (replaces hipMemsetAsync dispatch)
        ssum[tid] = 0.f;
        ssumsq[tid] = 0.f;
    }
}

// ---- GEMM v3 (reverted to the measured-44us R2 config): A register-resident
// for full K, B double-buffered; 16 MFMA : 4 loads per kc step. R3's v5
// (smaller tile, more waves) regressed to 60us: FETCH doubled (A re-read) and
// MFMA:load ratio collapsed -> keep the ILP-heavy structure.
__global__ __launch_bounds__(256, 2) void k_gemm(
    const _Float16* __restrict__ A, const _Float16* __restrict__ B,
    const float* __restrict__ br, const float* __restrict__ bi,
    _Float16* __restrict__ H)
{
    int bid = blockIdx.x;
    int bm = bid >> 1, cs = bid & 1;          // 235 x 2 blocks
    int tid = threadIdx.x;
    int lane = tid & 63, wave = tid >> 6;
    int quad = lane >> 4, l16 = lane & 15;
    int wm = wave >> 1, wn = wave & 1;        // wm: row half, wn: re/im
    int row0 = bm * 128 + wm * 64;

    f16x8 af[4][8];
#pragma unroll
    for (int mi = 0; mi < 4; mi++) {
        int r = row0 + mi * 16 + l16;
        if (r >= N_NODES) r = N_NODES - 1;    // clamp: garbage rows never stored
        const _Float16* ap = A + r * NC + quad * 8;
#pragma unroll
        for (int kc = 0; kc < 8; kc++)
            af[mi][kc] = *reinterpret_cast<const f16x8*>(ap + kc * 32);
    }

    const float* bias_p = wn ? bi : br;
#pragma unroll
    for (int cn = 0; cn < 2; cn++) {
        const _Float16* bbase = B + ((wn ? 256 : 0) + cs * 128 + cn * 64 + l16) * NC
                                  + quad * 8;
        f16x8 bb[2][4];
#pragma unroll
        for (int ni = 0; ni < 4; ni++)
            bb[0][ni] = *reinterpret_cast<const f16x8*>(bbase + ni * 16 * NC);
        f32x4 acc[4][4] = {};
#pragma unroll
        for (int kc = 0; kc < 8; kc++) {
            int cur = kc & 1, nxt = cur ^ 1;
            if (kc < 7) {
#pragma unroll
                for (int ni = 0; ni < 4; ni++)
                    bb[nxt][ni] = *reinterpret_cast<const f16x8*>(
                        bbase + ni * 16 * NC + (kc + 1) * 32);
            }
#pragma unroll
            for (int mi = 0; mi < 4; mi++)
#pragma unroll
                for (int ni = 0; ni < 4; ni++)
                    acc[mi][ni] = __builtin_amdgcn_mfma_f32_16x16x32_f16(
                        af[mi][kc], bb[cur][ni], acc[mi][ni], 0, 0, 0);
        }
#pragma unroll
        for (int ni = 0; ni < 4; ni++) {
            int c = cs * 128 + cn * 64 + ni * 16 + l16;
            float bias = bias_p[c];
            int cc = 2 * c + wn;
#pragma unroll
            for (int mi = 0; mi < 4; mi++) {
                int rowb = row0 + mi * 16 + quad * 4;
#pragma unroll
                for (int r = 0; r < 4; r++) {
                    int row = rowb + r;
                    if (row < N_NODES)
                        H[row * 512 + cc] = (_Float16)(acc[mi][ni][r] + bias);
                }
            }
        }
    }
}

// ---- evolve v4: NPB=60 / 512 threads (8 groups) / 500 blocks; coef precomputed
// by k_pre; 2-deep software pipeline on the j-loop. (R2: dropped out of top-5.)
#define NPB 60
#define NGRP 8
__global__ __launch_bounds__(512) void k_evolve(
    const float* __restrict__ x, const int* __restrict__ sub_nodes,
    const float* __restrict__ c4, const _Float16* __restrict__ h,
    const float* __restrict__ escp,
    float* __restrict__ outz, _Float16* __restrict__ zbuf, int use_f16,
    float* __restrict__ ssum, float* __restrict__ ssumsq)
{
    __shared__ int   s_nodes[NPB][4];
    __shared__ float s_P[NPB][4];
    __shared__ float s_redA[NGRP][256];
    __shared__ float s_redB[NGRP][256];
    int tid = threadIdx.x;
    int g = tid >> 6, lane = tid & 63;
    int base = blockIdx.x * NPB;      // 30000 = 500*60 exactly
    if (tid < NPB) {
        int node = base + tid;
        *reinterpret_cast<float4*>(&s_P[tid][0]) =
            *reinterpret_cast<const float4*>(c4 + node * 4);
        *reinterpret_cast<int4*>(&s_nodes[tid][0]) =
            *reinterpret_cast<const int4*>(sub_nodes + node * 4);
    }
    __syncthreads();
    float esc = *escp;
    float lsum[4] = {0.f, 0.f, 0.f, 0.f};
    float lsq[4]  = {0.f, 0.f, 0.f, 0.f};

    f16x8 hvA[4];
    float4 xA;
    int j = g;
#pragma unroll
    for (int s = 0; s < 4; s++)
        hvA[s] = *reinterpret_cast<const f16x8*>(h + s_nodes[j][s] * 512 + lane * 8);
    xA = *reinterpret_cast<const float4*>(x + (base + j) * NC + lane * 4);

    for (;;) {
        int jn = j + NGRP;
        bool more = jn < NPB;
        f16x8 hvB[4];
        float4 xB;
        if (more) {
#pragma unroll
            for (int s = 0; s < 4; s++)
                hvB[s] = *reinterpret_cast<const f16x8*>(
                    h + s_nodes[jn][s] * 512 + lane * 8);
            xB = *reinterpret_cast<const float4*>(x + (base + jn) * NC + lane * 4);
        }
        // ---- compute node j from hvA/xA ----
        {
            int node = base + j;
            float P0 = s_P[j][0], P1 = s_P[j][1], P2 = s_P[j][2], P3 = s_P[j][3];
            float xr[4] = {xA.x, xA.y, xA.z, xA.w};
            f16x8 zo;
            float or4[4], oi4[4];
#pragma unroll
            for (int e = 0; e < 4; e++) {
                float hr0 = (float)hvA[0][2 * e], hi0 = (float)hvA[0][2 * e + 1];
                float hr1 = (float)hvA[1][2 * e], hi1 = (float)hvA[1][2 * e + 1];
                float hr2 = (float)hvA[2][2 * e], hi2 = (float)hvA[2][2 * e + 1];
                float hr3 = (float)hvA[3][2 * e], hi3 = (float)hvA[3][2 * e + 1];
                float er = esc * hr0;             // identity (self) term, m0==1
                float ei = esc * hi0;
                er = fmaf(P0, hi0, er); ei = fmaf(-P0, hr0, ei);
                er = fmaf(P1, hi1, er); ei = fmaf(-P1, hr1, ei);
                er = fmaf(P2, hi2, er); ei = fmaf(-P2, hr2, ei);
                er = fmaf(P3, hi3, er); ei = fmaf(-P3, hr3, ei);
                float outr = er + xr[e];
                float outi = ei;
                or4[e] = outr; oi4[e] = outi;
                zo[2 * e] = (_Float16)outr; zo[2 * e + 1] = (_Float16)outi;
                float mag = sqrtf(fmaf(outr, outr, fmaf(outi, outi, 1e-5f)));
                mag = fminf(fmaxf(mag, 1e-5f), 1000.f);
                lsum[e] += mag;
                lsq[e] = fmaf(mag, mag, lsq[e]);
            }
            if (use_f16) {
                *reinterpret_cast<f16x8*>(zbuf + node * 512 + lane * 8) = zo;
            } else {
                *reinterpret_cast<float4*>(outz + node * 512 + lane * 4) =
                    make_float4(or4[0], or4[1], or4[2], or4[3]);
                *reinterpret_cast<float4*>(outz + node * 512 + 256 + lane * 4) =
                    make_float4(oi4[0], oi4[1], oi4[2], oi4[3]);
            }
        }
        if (!more) break;
#pragma unroll
        for (int s = 0; s < 4; s++) hvA[s] = hvB[s];
        xA = xB;
        j = jn;
    }
#pragma unroll
    for (int e = 0; e < 4; e++) {
        s_redA[g][lane * 4 + e] = lsum[e];
        s_redB[g][lane * 4 + e] = lsq[e];
    }
    __syncthreads();
    if (tid < 256) {
        float a = 0.f;
#pragma unroll
        for (int q = 0; q < NGRP; q++) a += s_redA[q][tid];
        atomicAdd(&ssum[tid], a);          // tid == channel; 500 adds per address
    } else {
        int t = tid - 256;
        float b = 0.f;
#pragma unroll
        for (int q = 0; q < NGRP; q++) b += s_redB[q][t];
        atomicAdd(&ssumsq[t], b);
    }
}

// ---- layernorm + phase + leaky crelu; stats affine recomputed inline ----
__global__ __launch_bounds__(256) void k_norm(
    float* __restrict__ out, const _Float16* __restrict__ zbuf, int use_f16,
    const float* __restrict__ ssum, const float* __restrict__ ssumsq,
    const float* __restrict__ lnw, const float* __restrict__ lnb)
{
    int tid = threadIdx.x;
    int node = blockIdx.x * 4 + (tid >> 6);        // 7500 blocks
    int c0 = (tid & 63) * 4;
    float re[4], im[4];
    if (use_f16) {
        f16x8 z = *reinterpret_cast<const f16x8*>(zbuf + node * 512 + c0 * 2);
#pragma unroll
        for (int e = 0; e < 4; e++) { re[e] = (float)z[2 * e]; im[e] = (float)z[2 * e + 1]; }
    } else {
        float4 r4 = *reinterpret_cast<const float4*>(out + node * 512 + c0);
        float4 i4 = *reinterpret_cast<const float4*>(out + node * 512 + 256 + c0);
        re[0] = r4.x; re[1] = r4.y; re[2] = r4.z; re[3] = r4.w;
        im[0] = i4.x; im[1] = i4.y; im[2] = i4.z; im[3] = i4.w;
    }
    float4 s4 = *reinterpret_cast<const float4*>(ssum + c0);
    float4 q4 = *reinterpret_cast<const float4*>(ssumsq + c0);
    float4 w4 = *reinterpret_cast<const float4*>(lnw + c0);
    float4 lb4 = *reinterpret_cast<const float4*>(lnb + c0);
    float S[4] = {s4.x, s4.y, s4.z, s4.w};
    float Q[4] = {q4.x, q4.y, q4.z, q4.w};
    float W[4] = {w4.x, w4.y, w4.z, w4.w};
    float L[4] = {lb4.x, lb4.y, lb4.z, lb4.w};
    const float invN = 1.0f / (float)N_NODES;
    float orr[4], oii[4];
#pragma unroll
    for (int e = 0; e < 4; e++) {
        float mean = S[e] * invN;
        float var = fmaxf(Q[e] * invN - mean * mean, 0.f);
        float denom = sqrtf(var + 1e-5f) + 1e-5f;
        float A = fabsf(W[e]) / denom;
        float Bc = L[e] - mean * A;
        float r = re[e], i = im[e];
        float mag = sqrtf(fmaf(r, r, fmaf(i, i, 1e-5f)));
        mag = fminf(fmaxf(mag, 1e-5f), 1000.f);
        float sm = fmaf(mag, A, Bc);
        sm = fminf(fmaxf(sm, 1e-5f), 10.0f);
        float px = fminf(fmaxf(r, -1e6f), 1e6f) + 1e-10f;
        float py = fminf(fmaxf(i, -1e6f), 1e6f);
        float r2 = fmaf(px, px, py * py);
        float inv = rsqrtf(r2);
        float zr = sm * px * inv, zi = sm * py * inv;
        zr = fminf(fmaxf(zr, -5.f), 5.f);
        zi = fminf(fmaxf(zi, -5.f), 5.f);
        orr[e] = zr > 0.f ? zr : 0.01f * zr;
        oii[e] = zi > 0.f ? zi : 0.01f * zi;
    }
    *reinterpret_cast<float4*>(out + node * 512 + c0) =
        make_float4(orr[0], orr[1], orr[2], orr[3]);
    *reinterpret_cast<float4*>(out + node * 512 + 256 + c0) =
        make_float4(oii[0], oii[1], oii[2], oii[3]);
}

extern "C" void kernel_launch(void* const* d_in, const int* in_sizes, int n_in,
                              void* d_out, int out_size, void* d_ws, size_t ws_size,
                              hipStream_t stream) {
    const float* x        = (const float*)d_in[0];
    // d_in[1] edge_index: unused (sub_nodes/sub_mask/sub_H are precomputed)
    const int*   sub_nodes = (const int*)d_in[2];
    const float* sub_mask  = (const float*)d_in[3];
    const float* subH      = (const float*)d_in[4];
    const float* wr  = (const float*)d_in[5];
    const float* wi  = (const float*)d_in[6];
    const float* br  = (const float*)d_in[7];
    const float* bi  = (const float*)d_in[8];
    const float* lnw = (const float*)d_in[9];
    const float* lnb = (const float*)d_in[10];
    const float* esc = (const float*)d_in[11];
    float* out = (float*)d_out;

    char* ws = (char*)d_ws;
    const size_t XB_OFF   = 0;                    // 30000*256*2  = 15,360,000
    const size_t WB_OFF   = 15360000;             // 512*256*2    =    262,144
    const size_t H_OFF    = 15622144;             // 30000*512*2  = 30,720,000
    const size_t STAT_OFF = 46342144;             // 2 * 1024 (alloc 4096)
    const size_t C4_OFF   = 46346240;             // 30000*16     =    480,000
    const size_t ZB_OFF   = 46826240;             // 30000*512*2  = 30,720,000 (optional)
    const size_t WS_NEED_F16 = ZB_OFF + 30720000; // 77,546,240
    _Float16* xb = (_Float16*)(ws + XB_OFF);
    _Float16* Wb = (_Float16*)(ws + WB_OFF);
    _Float16* h  = (_Float16*)(ws + H_OFF);
    float* ssum   = (float*)(ws + STAT_OFF);
    float* ssumsq = (float*)(ws + STAT_OFF + 1024);
    float* c4     = (float*)(ws + C4_OFF);
    _Float16* zbuf = (_Float16*)(ws + ZB_OFF);
    int use_f16 = (ws_size >= WS_NEED_F16) ? 1 : 0;

    hipLaunchKernelGGL(k_pre, dim3(NBX + NBW + NBP + 1), dim3(256), 0, stream,
                       x, xb, wr, wi, Wb, subH, sub_mask, esc, c4, ssum, ssumsq);
    hipLaunchKernelGGL(k_gemm, dim3(235 * 2), dim3(256), 0, stream, xb, Wb, br, bi, h);
    hipLaunchKernelGGL(k_evolve, dim3(500), dim3(512), 0, stream,
                       x, sub_nodes, c4, h, esc, out, zbuf, use_f16,
                       ssum, ssumsq);
    hipLaunchKernelGGL(k_norm, dim3(7500), dim3(256), 0, stream,
                       out, zbuf, use_f16, ssum, ssumsq, lnw, lnb);
}